// Round 7
// baseline (176.677 us; speedup 1.0000x reference)
//
#include <hip/hip_runtime.h>
#include <hip/hip_bf16.h>

#define GK 1024

typedef __attribute__((ext_vector_type(8))) short bf16x8;
typedef __attribute__((ext_vector_type(4))) float f32x4;
typedef __attribute__((ext_vector_type(16))) float f32x16;
typedef __attribute__((ext_vector_type(4))) unsigned short ushort4v;

__device__ __forceinline__ f32x4 mfma16(bf16x8 a, bf16x8 b, f32x4 c) {
  return __builtin_amdgcn_mfma_f32_16x16x32_bf16(a, b, c, 0, 0, 0);
}
__device__ __forceinline__ f32x16 mfma32(bf16x8 a, bf16x8 b, f32x16 c) {
  return __builtin_amdgcn_mfma_f32_32x32x16_bf16(a, b, c, 0, 0, 0);
}

__device__ __forceinline__ unsigned short f2b(float f) {
  union { float f; unsigned int u; } x; x.f = f;
  return (unsigned short)((x.u + 0x7fffu + ((x.u >> 16) & 1u)) >> 16);
}

// packed f32x2 -> bf16x2 (RNE); lowers to v_cvt_pk_bf16_f32
__device__ __forceinline__ unsigned int pk2(float lo, float hi) {
  float2 f; f.x = lo; f.y = hi;
  __hip_bfloat162 t = __float22bfloat162_rn(f);
  union { __hip_bfloat162 b; unsigned int u; } c; c.b = t;
  return c.u;
}

__device__ __forceinline__ float fexp2(float x) {
#if __has_builtin(__builtin_amdgcn_exp2f)
  return __builtin_amdgcn_exp2f(x);
#else
  return exp2f(x);
#endif
}
__device__ __forceinline__ float frcp(float x) {
#if __has_builtin(__builtin_amdgcn_rcpf)
  return __builtin_amdgcn_rcpf(x);
#else
  return 1.0f / x;
#endif
}

// async global->LDS, 16B per lane; LDS dest = wave-uniform base + lane*16
__device__ __forceinline__ void gl_lds16(const unsigned short* g, void* l) {
  __builtin_amdgcn_global_load_lds(
      (const __attribute__((address_space(1))) unsigned int*)g,
      (__attribute__((address_space(3))) unsigned int*)l, 16, 0, 0);
}
__device__ __forceinline__ void gl_lds16f(const float* g, void* l) {
  __builtin_amdgcn_global_load_lds(
      (const __attribute__((address_space(1))) unsigned int*)g,
      (__attribute__((address_space(3))) unsigned int*)l, 16, 0, 0);
}

// ---------------- convert fp32 -> bf16 (inp + 4 weight mats) ----------------
__global__ __launch_bounds__(256) void convert_kernel(
    const float* __restrict__ inp,
    const float* __restrict__ wq, const float* __restrict__ wk,
    const float* __restrict__ wv, const float* __restrict__ wo,
    unsigned short* __restrict__ Xb, unsigned short* __restrict__ Wcat)
{
  const size_t XN = (size_t)4194304;  // 2*2048*1024
  size_t i = ((size_t)blockIdx.x * 256 + threadIdx.x) * 4;
  const float* src; unsigned short* dst; size_t off;
  if (i < XN) {
    src = inp; dst = Xb; off = i;
  } else {
    size_t j = i - XN;
    int w = (int)(j >> 20);
    off = j & 1048575u;
    src = (w == 0) ? wq : (w == 1) ? wk : (w == 2) ? wv : wo;
    dst = Wcat + ((size_t)w << 20);
  }
  f32x4 v = *(const f32x4*)(src + off);
  ushort4v o;
#pragma unroll
  for (int t = 0; t < 4; ++t) o[t] = f2b(v[t]);
  *(ushort4v*)(dst + off) = o;
}

// ------------- GEMM mainloop via global_load_lds (m97 pattern) --------------
__device__ __forceinline__ void gemm_mainloop(
    const unsigned short* __restrict__ A, const unsigned short* __restrict__ Wt,
    int m0, int n0, int tid, unsigned short* As, unsigned short* Bs,
    f32x4 (&acc)[4][4])
{
  const int lane = tid & 63;
  const int wave = tid >> 6;
  const int wr = wave >> 1, wc = wave & 1;
  const int lq = lane & 15, g = lane >> 4;

  const int r_in = lane >> 2;          // 0..15
  const int c8 = (lane & 3) * 8;       // element col: 0,8,16,24

  const unsigned short* Ap0 = A + (size_t)(m0 + wave * 32 + r_in) * GK + c8;
  const unsigned short* Ap1 = Ap0 + (size_t)16 * GK;
  const unsigned short* Wp0 = Wt + (size_t)(n0 + wave * 32 + r_in) * GK + c8;
  const unsigned short* Wp1 = Wp0 + (size_t)16 * GK;
  unsigned short* As0 = As + wave * 1024;   // elements (2KB per wave)
  unsigned short* Bs0 = Bs + wave * 1024;

  for (int kt = 0; kt < GK / 32; ++kt) {
    const int k0 = kt * 32;
    __syncthreads();                       // prev tile's reads done
    gl_lds16(Ap0 + k0, As0);
    gl_lds16(Ap1 + k0, As0 + 512);
    gl_lds16(Wp0 + k0, Bs0);
    gl_lds16(Wp1 + k0, Bs0 + 512);
    __syncthreads();                       // drains vmcnt -> LDS valid
    bf16x8 af[4], bfr[4];
#pragma unroll
    for (int i = 0; i < 4; ++i)
      af[i] = *(const bf16x8*)(As + (wr * 64 + i * 16 + lq) * 32 + g * 8);
#pragma unroll
    for (int j = 0; j < 4; ++j)
      bfr[j] = *(const bf16x8*)(Bs + (wc * 64 + j * 16 + lq) * 32 + g * 8);
#pragma unroll
    for (int i = 0; i < 4; ++i)
#pragma unroll
      for (int j = 0; j < 4; ++j)
        acc[i][j] = mfma16(af[i], bfr[j], acc[i][j]);
  }
}

// ---------------- QKV projection GEMM (z: 0=Q, 1=K, 2=V-transposed) ----------
__global__ __launch_bounds__(256) void gemm_qkv(
    const unsigned short* __restrict__ X, const unsigned short* __restrict__ Wcat,
    unsigned short* __restrict__ Qb, unsigned short* __restrict__ Kb,
    unsigned short* __restrict__ Vt)
{
  __shared__ unsigned short As[4096];
  __shared__ unsigned short Bs[4096];
  f32x4 acc[4][4];
#pragma unroll
  for (int i = 0; i < 4; ++i)
#pragma unroll
    for (int j = 0; j < 4; ++j) acc[i][j] = (f32x4){0.f, 0.f, 0.f, 0.f};

  const int z = blockIdx.z;
  const int m0 = blockIdx.x * 128, n0 = blockIdx.y * 128;
  gemm_mainloop(X, Wcat + ((size_t)z << 20), m0, n0, (int)threadIdx.x, As, Bs, acc);

  const int lane = threadIdx.x & 63;
  const int wave = threadIdx.x >> 6;
  const int wr = wave >> 1, wc = wave & 1, lq = lane & 15, g = lane >> 4;

  if (z < 2) {
    unsigned short* C = z ? Kb : Qb;
#pragma unroll
    for (int i = 0; i < 4; ++i)
#pragma unroll
      for (int j = 0; j < 4; ++j) {
        int col = n0 + wc * 64 + j * 16 + lq;
#pragma unroll
        for (int r = 0; r < 4; ++r) {
          int row = m0 + wr * 64 + i * 16 + g * 4 + r;
          C[(size_t)row * 1024 + col] = f2b(acc[i][j][r]);
        }
      }
  } else {
    // V transposed: Vt[(b*1024 + n)][s], n = h*64+dk
#pragma unroll
    for (int i = 0; i < 4; ++i)
#pragma unroll
      for (int j = 0; j < 4; ++j) {
        int col = n0 + wc * 64 + j * 16 + lq;
        int row0 = m0 + wr * 64 + i * 16 + g * 4;
        int b = row0 >> 11;
        int s = row0 & 2047;
        ushort4v pv;
#pragma unroll
        for (int r = 0; r < 4; ++r) pv[r] = f2b(acc[i][j][r]);
        *(ushort4v*)(Vt + (size_t)(b * 1024 + col) * 2048 + s) = pv;
      }
  }
}

// ---------------- output projection GEMM (fp32 out) ----------------
__global__ __launch_bounds__(256) void gemm_out(
    const unsigned short* __restrict__ Ob, const unsigned short* __restrict__ Wo,
    float* __restrict__ out)
{
  __shared__ unsigned short As[4096];
  __shared__ unsigned short Bs[4096];
  f32x4 acc[4][4];
#pragma unroll
  for (int i = 0; i < 4; ++i)
#pragma unroll
    for (int j = 0; j < 4; ++j) acc[i][j] = (f32x4){0.f, 0.f, 0.f, 0.f};

  const int m0 = blockIdx.x * 128, n0 = blockIdx.y * 128;
  gemm_mainloop(Ob, Wo, m0, n0, (int)threadIdx.x, As, Bs, acc);

  const int lane = threadIdx.x & 63;
  const int wave = threadIdx.x >> 6;
  const int wr = wave >> 1, wc = wave & 1, lq = lane & 15, g = lane >> 4;
#pragma unroll
  for (int i = 0; i < 4; ++i)
#pragma unroll
    for (int j = 0; j < 4; ++j) {
      int col = n0 + wc * 64 + j * 16 + lq;
#pragma unroll
      for (int r = 0; r < 4; ++r) {
        int row = m0 + wr * 64 + i * 16 + g * 4 + r;
        out[(size_t)row * 1024 + col] = acc[i][j][r];
      }
    }
}

// -------- fused flash attention: LDS-staged, q-quad blocks, fixed-max -------
// Block = 4 adjacent q-tiles (wave w owns tile 4*i+w) of one (b,h); one shared
// k-loop: K(4KB)+V(4KB) staged cooperatively via global_load_lds (coalesced,
// inverse-swizzled source), each wave stages its own bias tile (4KB f32).
// Double-buffered, stage-issue before compute. Fragments via XOR-swizzled
// ds_read_b128 (2 lanes/bank = conflict-free). Fixed-max softmax (softcap
// bounds scores). Per-wave epilogue: transpose via own bias LDS region.
//
// LDS map (bytes): K[db]   = db*4096          (rows 32 x 8 chunks of 16B)
//                  V[db]   = 8192  + db*4096  (rows 64 x 4 chunks)
//                  B[db][w]= 16384 + db*16384 + w*4096 (rows 32 x 8 chunks f32)
__global__ __launch_bounds__(256) void attn_fwd(
    const unsigned short* __restrict__ Qb, const unsigned short* __restrict__ Kb,
    const unsigned short* __restrict__ Vt, const float* __restrict__ bias,
    unsigned short* __restrict__ Ob)
{
  __shared__ unsigned char lds[49152];

  const int tid = (int)threadIdx.x;
  const int lane = tid & 63;
  const int w = tid >> 6;
  // XCD swizzle: xcd = bid&7 owns heads [4*xcd,4*xcd+4); longest blocks first
  const int bid = (int)blockIdx.x;
  const int i = 15 - ((bid >> 3) & 15);
  const int bh = (bid & 7) * 4 + (bid >> 7);
  const int b = bh >> 4, h = bh & 15;
  const int myt = 4 * i + w;           // this wave's q-tile
  const int q0w = myt * 32;
  const int ktmax = 4 * i + 3;
  const int ql = lane & 31;
  const int hi = lane >> 5;

  // ---- Q fragments (one-time gather) ----
  const unsigned short* Qp = Qb + (size_t)(b * 2048 + q0w + ql) * 1024 + h * 64 + 8 * hi;
  bf16x8 qf[4];
#pragma unroll
  for (int c = 0; c < 4; ++c) qf[c] = *(const bf16x8*)(Qp + 16 * c);

  // ---- staging source addresses (inverse-swizzled, rule #21) ----
  // K: lane li -> local row 8w+(li>>3), chunk (li&7)^((li>>3)&7)
  const int kr = 8 * w + (lane >> 3);
  const int kcs = (lane & 7) ^ ((lane >> 3) & 7);
  const unsigned short* Ksrc = Kb + (size_t)(b * 2048 + kr) * 1024 + h * 64 + kcs * 8;
  // V: lane li -> row 16w+(li>>2), chunk (li&3)^((li>>2)&3)
  const int vd = 16 * w + (lane >> 2);
  const int vcs = (lane & 3) ^ ((lane >> 2) & 3);
  const unsigned short* Vsrc = Vt + (size_t)(bh * 64 + vd) * 2048 + vcs * 8;
  // bias: per-wave tile; instr j covers rows 8j..8j+8
  const int br = lane >> 3;
  const int bcs = (lane & 7) ^ ((lane >> 3) & 7);
  const float* Bsrc = bias + (size_t)b * 4194304 + (size_t)(q0w + br) * 2048 + bcs * 4;

  unsigned char* const Kdst = lds + w * 1024;           // + db*4096
  unsigned char* const Vdst = lds + 8192 + w * 1024;    // + db*4096
  unsigned char* const Bdst = lds + 16384 + w * 4096;   // + db*16384 + j*1024

  const float INV30 = 0.033333333333f;
  const float C3 = -0.333333333f, C5 = 0.133333333f;
  const float C1 = 43.28085122666891f;   // 30*log2(e)

  float pls = 0.f;
  f32x16 oT0 = {0.f,0.f,0.f,0.f,0.f,0.f,0.f,0.f,0.f,0.f,0.f,0.f,0.f,0.f,0.f,0.f};
  f32x16 oT1 = oT0;

  auto stage = [&](int kt, int db) {
    gl_lds16(Ksrc + (size_t)kt * 32768, Kdst + db * 4096);
    gl_lds16(Vsrc + kt * 32, Vdst + db * 4096);
    if (kt <= myt) {  // wave-uniform; skip bias for finished waves
#pragma unroll
      for (int j = 0; j < 4; ++j)
        gl_lds16f(Bsrc + kt * 32 + j * 16384, Bdst + db * 16384 + j * 1024);
    }
  };

  // prologue
  stage(0, 0);
  __syncthreads();

  int cur = 0;
  for (int kt = 0; kt <= ktmax; ++kt) {
    if (kt < ktmax) stage(kt + 1, cur ^ 1);

    if (kt <= myt) {
      const unsigned char* Ksh = lds + cur * 4096;
      const unsigned char* Vsh = lds + 8192 + cur * 4096;
      const unsigned char* Bsh = lds + 16384 + cur * 16384 + w * 4096;
      const int q7 = (ql & 7) << 4;     // byte swizzle within 128B row
      const int q3 = (ql & 3) << 4;     // byte swizzle within 64B row

      // K fragments: row ql, chunks g=hi+2c, read slot g^(ql&7)
      bf16x8 kf[4];
#pragma unroll
      for (int c = 0; c < 4; ++c)
        kf[c] = *(const bf16x8*)(Ksh + ql * 128 + (((hi + 2 * c) << 4) ^ q7));
      // bias: chunks g=hi+2j
      f32x4 bvs[4];
#pragma unroll
      for (int j = 0; j < 4; ++j)
        bvs[j] = *(const f32x4*)(Bsh + ql * 128 + (((hi + 2 * j) << 4) ^ q7));
      // V fragments: rows ql / 32+ql, chunks g=hi, hi+2 (<4), slot g^(ql&3)
      bf16x8 va00 = *(const bf16x8*)(Vsh + ql * 64 + ((hi << 4) ^ q3));
      bf16x8 va01 = *(const bf16x8*)(Vsh + ql * 64 + (((hi + 2) << 4) ^ q3));
      bf16x8 va10 = *(const bf16x8*)(Vsh + (32 + ql) * 64 + ((hi << 4) ^ q3));
      bf16x8 va11 = *(const bf16x8*)(Vsh + (32 + ql) * 64 + (((hi + 2) << 4) ^ q3));

      f32x16 st = {0.f,0.f,0.f,0.f,0.f,0.f,0.f,0.f,0.f,0.f,0.f,0.f,0.f,0.f,0.f,0.f};
      st = mfma32(kf[0], qf[0], st);
      st = mfma32(kf[1], qf[1], st);
      st = mfma32(kf[2], qf[2], st);
      st = mfma32(kf[3], qf[3], st);

      float p[16];
#pragma unroll
      for (int reg = 0; reg < 16; ++reg) {
        float v = fmaf(st[reg], 0.125f, bvs[reg >> 2][reg & 3]);
        float y = v * INV30;
        float y2 = y * y;
        float t = y * fmaf(y2, fmaf(y2, C5, C3), 1.0f);
        p[reg] = fexp2(fmaf(t, C1, -C1));
      }
      if (kt == myt) {  // diagonal: causal mask
#pragma unroll
        for (int reg = 0; reg < 16; ++reg) {
          int krow = (reg & 3) + 8 * (reg >> 2) + 4 * hi;
          p[reg] = (krow <= ql) ? p[reg] : 0.f;
        }
      }
      float a0 = (p[0] + p[1]) + (p[2] + p[3]);
      float a1 = (p[4] + p[5]) + (p[6] + p[7]);
      float a2 = (p[8] + p[9]) + (p[10] + p[11]);
      float a3 = (p[12] + p[13]) + (p[14] + p[15]);
      pls += (a0 + a1) + (a2 + a3);

      unsigned int wv[8];
#pragma unroll
      for (int j = 0; j < 8; ++j) wv[j] = pk2(p[2 * j], p[2 * j + 1]);
      unsigned int x0 = hi ? wv[0] : wv[2], x1 = hi ? wv[1] : wv[3];
      x0 = __shfl_xor(x0, 32); x1 = __shfl_xor(x1, 32);
      unsigned int y0 = hi ? wv[4] : wv[6], y1 = hi ? wv[5] : wv[7];
      y0 = __shfl_xor(y0, 32); y1 = __shfl_xor(y1, 32);
      union { unsigned int u[4]; bf16x8 v; } B0, B1;
      B0.u[0] = hi ? x0 : wv[0]; B0.u[1] = hi ? x1 : wv[1];
      B0.u[2] = hi ? wv[2] : x0; B0.u[3] = hi ? wv[3] : x1;
      B1.u[0] = hi ? y0 : wv[4]; B1.u[1] = hi ? y1 : wv[5];
      B1.u[2] = hi ? wv[6] : y0; B1.u[3] = hi ? wv[7] : y1;

      oT0 = mfma32(va00, B0.v, oT0);
      oT0 = mfma32(va01, B1.v, oT0);
      oT1 = mfma32(va10, B0.v, oT1);
      oT1 = mfma32(va11, B1.v, oT1);
    }

    __syncthreads();   // drains staged vmcnt; buf[cur] reads complete
    cur ^= 1;
  }

  // ---- per-wave epilogue: rowsum, scale, transpose via own bias region ----
  pls += __shfl_xor(pls, 32);
  float rl = frcp(pls);
  unsigned short* T = (unsigned short*)(lds + 16384 + w * 4096); // [32 q][64 d]
#pragma unroll
  for (int r = 0; r < 16; r += 2) {
    int d0 = (r & 3) + 8 * (r >> 2) + 4 * hi;   // even
    *(unsigned int*)(T + ql * 64 + d0) = pk2(oT0[r] * rl, oT0[r + 1] * rl);
    *(unsigned int*)(T + ql * 64 + 32 + d0) = pk2(oT1[r] * rl, oT1[r + 1] * rl);
  }
  // coalesced store: 8 rows x 128B per pass
#pragma unroll
  for (int j = 0; j < 4; ++j) {
    int idx = j * 64 + lane;
    int q = idx >> 3, c = idx & 7;
    bf16x8 val = *(const bf16x8*)(T + q * 64 + c * 8);
    *(bf16x8*)(Ob + (size_t)(b * 2048 + q0w + q) * 1024 + h * 64 + c * 8) = val;
  }
}

extern "C" void kernel_launch(void* const* d_in, const int* in_sizes, int n_in,
                              void* d_out, int out_size, void* d_ws, size_t ws_size,
                              hipStream_t stream) {
  (void)in_sizes; (void)n_in; (void)out_size; (void)ws_size;
  const float* inp  = (const float*)d_in[0];
  const float* bias = (const float*)d_in[1];
  // d_in[2] = attn_mask (causal, recomputed in-kernel)
  const float* wq = (const float*)d_in[3];
  const float* wk = (const float*)d_in[4];
  const float* wv = (const float*)d_in[5];
  const float* wo = (const float*)d_in[6];
  float* out = (float*)d_out;

  unsigned short* Xb   = (unsigned short*)d_ws;     // 4096x1024 bf16
  unsigned short* Wcat = Xb + 4194304;              // 4 x 1024x1024 bf16
  unsigned short* Qb   = Wcat + 4194304;            // 4096x1024
  unsigned short* Kb   = Qb + 4194304;              // 4096x1024
  unsigned short* Vt   = Kb + 4194304;              // (2*16*64) x 2048
  unsigned short* Ob   = Vt + 4194304;              // 4096x1024

  convert_kernel<<<8192, 256, 0, stream>>>(inp, wq, wk, wv, wo, Xb, Wcat);
  gemm_qkv<<<dim3(32, 8, 3), dim3(256), 0, stream>>>(Xb, Wcat, Qb, Kb, Vt);
  attn_fwd<<<512, 256, 0, stream>>>(Qb, Kb, Vt, bias, Ob);
  gemm_out<<<dim3(32, 8, 1), dim3(256), 0, stream>>>(Ob, Wcat + 3 * 1048576, out);
}

// Round 8
// 140.522 us; speedup vs baseline: 1.2573x; 1.2573x over previous
//
#include <hip/hip_runtime.h>
#include <hip/hip_bf16.h>

#define GK 1024

typedef __attribute__((ext_vector_type(8))) short bf16x8;
typedef __attribute__((ext_vector_type(4))) float f32x4;
typedef __attribute__((ext_vector_type(16))) float f32x16;
typedef __attribute__((ext_vector_type(4))) unsigned short ushort4v;

__device__ __forceinline__ f32x4 mfma16(bf16x8 a, bf16x8 b, f32x4 c) {
  return __builtin_amdgcn_mfma_f32_16x16x32_bf16(a, b, c, 0, 0, 0);
}
__device__ __forceinline__ f32x16 mfma32(bf16x8 a, bf16x8 b, f32x16 c) {
  return __builtin_amdgcn_mfma_f32_32x32x16_bf16(a, b, c, 0, 0, 0);
}

__device__ __forceinline__ unsigned short f2b(float f) {
  union { float f; unsigned int u; } x; x.f = f;
  return (unsigned short)((x.u + 0x7fffu + ((x.u >> 16) & 1u)) >> 16);
}

// packed f32x2 -> bf16x2 (RNE); lowers to v_cvt_pk_bf16_f32
__device__ __forceinline__ unsigned int pk2(float lo, float hi) {
  float2 f; f.x = lo; f.y = hi;
  __hip_bfloat162 t = __float22bfloat162_rn(f);
  union { __hip_bfloat162 b; unsigned int u; } c; c.b = t;
  return c.u;
}

__device__ __forceinline__ float fexp2(float x) {
#if __has_builtin(__builtin_amdgcn_exp2f)
  return __builtin_amdgcn_exp2f(x);
#else
  return exp2f(x);
#endif
}
__device__ __forceinline__ float frcp(float x) {
#if __has_builtin(__builtin_amdgcn_rcpf)
  return __builtin_amdgcn_rcpf(x);
#else
  return 1.0f / x;
#endif
}

// async global->LDS, 16B per lane; LDS dest = wave-uniform base + lane*16
__device__ __forceinline__ void gl_lds16(const void* g, void* l) {
  __builtin_amdgcn_global_load_lds(
      (const __attribute__((address_space(1))) unsigned int*)g,
      (__attribute__((address_space(3))) unsigned int*)l, 16, 0, 0);
}

// ---------------- convert fp32 -> bf16 (inp + 4 weight mats) ----------------
__global__ __launch_bounds__(256) void convert_kernel(
    const float* __restrict__ inp,
    const float* __restrict__ wq, const float* __restrict__ wk,
    const float* __restrict__ wv, const float* __restrict__ wo,
    unsigned short* __restrict__ Xb, unsigned short* __restrict__ Wcat)
{
  const size_t XN = (size_t)4194304;  // 2*2048*1024
  size_t i = ((size_t)blockIdx.x * 256 + threadIdx.x) * 4;
  const float* src; unsigned short* dst; size_t off;
  if (i < XN) {
    src = inp; dst = Xb; off = i;
  } else {
    size_t j = i - XN;
    int w = (int)(j >> 20);
    off = j & 1048575u;
    src = (w == 0) ? wq : (w == 1) ? wk : (w == 2) ? wv : wo;
    dst = Wcat + ((size_t)w << 20);
  }
  f32x4 v = *(const f32x4*)(src + off);
  ushort4v o;
#pragma unroll
  for (int t = 0; t < 4; ++t) o[t] = f2b(v[t]);
  *(ushort4v*)(dst + off) = o;
}

// ------------- GEMM mainloop via global_load_lds (m97 pattern) --------------
__device__ __forceinline__ void gemm_mainloop(
    const unsigned short* __restrict__ A, const unsigned short* __restrict__ Wt,
    int m0, int n0, int tid, unsigned short* As, unsigned short* Bs,
    f32x4 (&acc)[4][4])
{
  const int lane = tid & 63;
  const int wave = tid >> 6;
  const int wr = wave >> 1, wc = wave & 1;
  const int lq = lane & 15, g = lane >> 4;

  const int r_in = lane >> 2;          // 0..15
  const int c8 = (lane & 3) * 8;       // element col: 0,8,16,24

  const unsigned short* Ap0 = A + (size_t)(m0 + wave * 32 + r_in) * GK + c8;
  const unsigned short* Ap1 = Ap0 + (size_t)16 * GK;
  const unsigned short* Wp0 = Wt + (size_t)(n0 + wave * 32 + r_in) * GK + c8;
  const unsigned short* Wp1 = Wp0 + (size_t)16 * GK;
  unsigned short* As0 = As + wave * 1024;   // elements (2KB per wave)
  unsigned short* Bs0 = Bs + wave * 1024;

  for (int kt = 0; kt < GK / 32; ++kt) {
    const int k0 = kt * 32;
    __syncthreads();                       // prev tile's reads done
    gl_lds16(Ap0 + k0, As0);
    gl_lds16(Ap1 + k0, As0 + 512);
    gl_lds16(Wp0 + k0, Bs0);
    gl_lds16(Wp1 + k0, Bs0 + 512);
    __syncthreads();                       // drains vmcnt -> LDS valid
    bf16x8 af[4], bfr[4];
#pragma unroll
    for (int i = 0; i < 4; ++i)
      af[i] = *(const bf16x8*)(As + (wr * 64 + i * 16 + lq) * 32 + g * 8);
#pragma unroll
    for (int j = 0; j < 4; ++j)
      bfr[j] = *(const bf16x8*)(Bs + (wc * 64 + j * 16 + lq) * 32 + g * 8);
#pragma unroll
    for (int i = 0; i < 4; ++i)
#pragma unroll
      for (int j = 0; j < 4; ++j)
        acc[i][j] = mfma16(af[i], bfr[j], acc[i][j]);
  }
}

// ---------------- QKV projection GEMM (z: 0=Q, 1=K, 2=V-transposed) ----------
__global__ __launch_bounds__(256) void gemm_qkv(
    const unsigned short* __restrict__ X, const unsigned short* __restrict__ Wcat,
    unsigned short* __restrict__ Qb, unsigned short* __restrict__ Kb,
    unsigned short* __restrict__ Vt)
{
  __shared__ unsigned short As[4096];
  __shared__ unsigned short Bs[4096];
  f32x4 acc[4][4];
#pragma unroll
  for (int i = 0; i < 4; ++i)
#pragma unroll
    for (int j = 0; j < 4; ++j) acc[i][j] = (f32x4){0.f, 0.f, 0.f, 0.f};

  const int z = blockIdx.z;
  const int m0 = blockIdx.x * 128, n0 = blockIdx.y * 128;
  gemm_mainloop(X, Wcat + ((size_t)z << 20), m0, n0, (int)threadIdx.x, As, Bs, acc);

  const int lane = threadIdx.x & 63;
  const int wave = threadIdx.x >> 6;
  const int wr = wave >> 1, wc = wave & 1, lq = lane & 15, g = lane >> 4;

  if (z < 2) {
    unsigned short* C = z ? Kb : Qb;
#pragma unroll
    for (int i = 0; i < 4; ++i)
#pragma unroll
      for (int j = 0; j < 4; ++j) {
        int col = n0 + wc * 64 + j * 16 + lq;
#pragma unroll
        for (int r = 0; r < 4; ++r) {
          int row = m0 + wr * 64 + i * 16 + g * 4 + r;
          C[(size_t)row * 1024 + col] = f2b(acc[i][j][r]);
        }
      }
  } else {
    // V transposed: Vt[(b*1024 + n)][s], n = h*64+dk
#pragma unroll
    for (int i = 0; i < 4; ++i)
#pragma unroll
      for (int j = 0; j < 4; ++j) {
        int col = n0 + wc * 64 + j * 16 + lq;
        int row0 = m0 + wr * 64 + i * 16 + g * 4;
        int b = row0 >> 11;
        int s = row0 & 2047;
        ushort4v pv;
#pragma unroll
        for (int r = 0; r < 4; ++r) pv[r] = f2b(acc[i][j][r]);
        *(ushort4v*)(Vt + (size_t)(b * 1024 + col) * 2048 + s) = pv;
      }
  }
}

// ---------------- output projection GEMM (fp32 out) ----------------
__global__ __launch_bounds__(256) void gemm_out(
    const unsigned short* __restrict__ Ob, const unsigned short* __restrict__ Wo,
    float* __restrict__ out)
{
  __shared__ unsigned short As[4096];
  __shared__ unsigned short Bs[4096];
  f32x4 acc[4][4];
#pragma unroll
  for (int i = 0; i < 4; ++i)
#pragma unroll
    for (int j = 0; j < 4; ++j) acc[i][j] = (f32x4){0.f, 0.f, 0.f, 0.f};

  const int m0 = blockIdx.x * 128, n0 = blockIdx.y * 128;
  gemm_mainloop(Ob, Wo, m0, n0, (int)threadIdx.x, As, Bs, acc);

  const int lane = threadIdx.x & 63;
  const int wave = threadIdx.x >> 6;
  const int wr = wave >> 1, wc = wave & 1, lq = lane & 15, g = lane >> 4;
#pragma unroll
  for (int i = 0; i < 4; ++i)
#pragma unroll
    for (int j = 0; j < 4; ++j) {
      int col = n0 + wc * 64 + j * 16 + lq;
#pragma unroll
      for (int r = 0; r < 4; ++r) {
        int row = m0 + wr * 64 + i * 16 + g * 4 + r;
        out[(size_t)row * 1024 + col] = acc[i][j][r];
      }
    }
}

// ---------------- attention tile chain: softcap + pack + PV ----------------
// Poly-tanh softcap: p = exp2(C1*tanh(y) - C1), y = (raw/8 + bias)/30.
__device__ __forceinline__ void attn_chain(
    const bf16x8 (&qf)[4], const f32x4 (&bvs)[4],
    bf16x8 kf0, bf16x8 kf1, bf16x8 kf2, bf16x8 kf3,
    bf16x8 va00, bf16x8 va01, bf16x8 va10, bf16x8 va11,
    bool msk, int ql, int hi,
    f32x16& o0, f32x16& o1, float& pls)
{
  const float INV30 = 0.033333333333f;
  const float C3 = -0.333333333f, C5 = 0.133333333f;
  const float C1 = 43.28085122666891f;   // 30*log2(e)

  f32x16 st = {0.f,0.f,0.f,0.f,0.f,0.f,0.f,0.f,0.f,0.f,0.f,0.f,0.f,0.f,0.f,0.f};
  st = mfma32(kf0, qf[0], st);
  st = mfma32(kf1, qf[1], st);
  st = mfma32(kf2, qf[2], st);
  st = mfma32(kf3, qf[3], st);

  float p[16];
#pragma unroll
  for (int reg = 0; reg < 16; ++reg) {
    float v = fmaf(st[reg], 0.125f, bvs[reg >> 2][reg & 3]);
    float y = v * INV30;
    float y2 = y * y;
    float t = y * fmaf(y2, fmaf(y2, C5, C3), 1.0f);
    p[reg] = fexp2(fmaf(t, C1, -C1));
  }
  if (msk) {
#pragma unroll
    for (int reg = 0; reg < 16; ++reg) {
      int krow = (reg & 3) + 8 * (reg >> 2) + 4 * hi;
      p[reg] = (krow <= ql) ? p[reg] : 0.f;
    }
  }
  float a0 = (p[0] + p[1]) + (p[2] + p[3]);
  float a1 = (p[4] + p[5]) + (p[6] + p[7]);
  float a2 = (p[8] + p[9]) + (p[10] + p[11]);
  float a3 = (p[12] + p[13]) + (p[14] + p[15]);
  pls += (a0 + a1) + (a2 + a3);

  unsigned int wv[8];
#pragma unroll
  for (int j = 0; j < 8; ++j) wv[j] = pk2(p[2 * j], p[2 * j + 1]);
  unsigned int x0 = hi ? wv[0] : wv[2], x1 = hi ? wv[1] : wv[3];
  x0 = __shfl_xor(x0, 32); x1 = __shfl_xor(x1, 32);
  unsigned int y0 = hi ? wv[4] : wv[6], y1 = hi ? wv[5] : wv[7];
  y0 = __shfl_xor(y0, 32); y1 = __shfl_xor(y1, 32);
  union { unsigned int u[4]; bf16x8 v; } B0, B1;
  B0.u[0] = hi ? x0 : wv[0]; B0.u[1] = hi ? x1 : wv[1];
  B0.u[2] = hi ? wv[2] : x0; B0.u[3] = hi ? wv[3] : x1;
  B1.u[0] = hi ? y0 : wv[4]; B1.u[1] = hi ? y1 : wv[5];
  B1.u[2] = hi ? wv[6] : y0; B1.u[3] = hi ? wv[7] : y1;

  o0 = mfma32(va00, B0.v, o0);
  o0 = mfma32(va01, B1.v, o0);
  o1 = mfma32(va10, B0.v, o1);
  o1 = mfma32(va11, B1.v, o1);
}

// ---- fused flash attention: symmetric q-pair, split-k x4, per-wave staged ----
// Block owns q-tiles tA=qp, tB=63-qp of one (b,h): exactly 65 chains/block
// (uniform grid of 1024). Wave w handles kt = w mod 4 for BOTH chains (2-chain
// ILP); each wave double-buffers ITS K/V tile in a private 16KB LDS region via
// global_load_lds (coalesced, inverse-swizzled). No barriers in the loop:
// per-wave s_waitcnt vmcnt(0) + sched_barrier (rule #18); next stage issued
// before compute. Bias = per-lane gather (read-once). Fixed-max softmax
// (softcap bounds scores) so partials sum; LDS combine epilogue (aliased).
__global__ __launch_bounds__(256, 2) void attn_fwd(
    const unsigned short* __restrict__ Qb, const unsigned short* __restrict__ Kb,
    const unsigned short* __restrict__ Vt, const float* __restrict__ bias,
    unsigned short* __restrict__ Ob)
{
  __shared__ __attribute__((aligned(16))) unsigned char lds[65536];

  const int tid = (int)threadIdx.x;
  const int lane = tid & 63;
  const int w = tid >> 6;
  // XCD affinity: xcd = bid&7 owns heads [4*xcd, 4*xcd+4)
  const int bid = (int)blockIdx.x;
  const int bh = (bid & 7) * 4 + ((bid >> 3) & 3);
  const int qp = bid >> 5;                 // 0..31
  const int b = bh >> 4, h = bh & 15;
  const int tA = qp, tB = 63 - qp;
  const int q0A = tA * 32, q0B = tB * 32;
  const int ql = lane & 31;
  const int hi = lane >> 5;

  // ---- Q fragments (one-time gather) ----
  const unsigned short* QpA = Qb + (size_t)(b * 2048 + q0A + ql) * 1024 + h * 64 + 8 * hi;
  const unsigned short* QpB = Qb + (size_t)(b * 2048 + q0B + ql) * 1024 + h * 64 + 8 * hi;
  bf16x8 qfA[4], qfB[4];
#pragma unroll
  for (int c = 0; c < 4; ++c) {
    qfA[c] = *(const bf16x8*)(QpA + 16 * c);
    qfB[c] = *(const bf16x8*)(QpB + 16 * c);
  }

  // ---- per-lane staging sources (inverse-swizzled, rule #21) ----
  // K tile [32 k-rows][8 chunks of 16B], slot s of row r holds chunk s^(r&7)
  const unsigned short* KsrcL = Kb + (size_t)(b * 2048 + (lane >> 3)) * 1024
                                + h * 64 + (((lane & 7) ^ ((lane >> 3) & 7)) << 3);
  // V tile [4 dgroups][16 rows][4 chunks of 16B], slot s of row d holds s^(d&3)
  const unsigned short* VsrcL = Vt + (size_t)(bh * 64 + (lane >> 2)) * 2048
                                + (((lane & 3) ^ ((lane >> 2) & 3)) << 3);
  unsigned char* const KdstW = lds + w * 16384;          // + db*4096 + j*1024
  unsigned char* const VdstW = lds + w * 16384 + 8192;   // + db*4096 + j*1024

  const float* BpA = bias + (size_t)b * 4194304 + (size_t)(q0A + ql) * 2048 + 4 * hi;
  const float* BpB = bias + (size_t)b * 4194304 + (size_t)(q0B + ql) * 2048 + 4 * hi;

  float plsA = 0.f, plsB = 0.f;
  f32x16 oA0 = {0.f,0.f,0.f,0.f,0.f,0.f,0.f,0.f,0.f,0.f,0.f,0.f,0.f,0.f,0.f,0.f};
  f32x16 oA1 = oA0, oB0 = oA0, oB1 = oA0;

  auto stageKV = [&](int kt, int db) {
#pragma unroll
    for (int j = 0; j < 4; ++j)
      gl_lds16(KsrcL + (size_t)kt * 32768 + j * 8192, KdstW + db * 4096 + j * 1024);
#pragma unroll
    for (int j = 0; j < 4; ++j)
      gl_lds16(VsrcL + (size_t)j * 32768 + kt * 32, VdstW + db * 4096 + j * 1024);
  };

  stageKV(w, 0);   // prologue: wave's first k-tile into buf 0
  int db = 0;
  for (int kt0 = 0; kt0 <= tB; kt0 += 4) {
    const int mykt = kt0 + w;
    asm volatile("s_waitcnt vmcnt(0)" ::: "memory");  // buf[db] staged & ready
    __builtin_amdgcn_sched_barrier(0);
    if (mykt + 4 <= tB) stageKV(mykt + 4, db ^ 1);    // prefetch next (in flight)
    __builtin_amdgcn_sched_barrier(0);

    if (mykt <= tB) {
      const unsigned char* Ksh = lds + w * 16384 + db * 4096;
      const unsigned char* Vsh = lds + w * 16384 + 8192 + db * 4096;
      // K fragments: row ql, chunk (hi+2c) at slot (hi+2c)^(ql&7)
      bf16x8 kf[4];
#pragma unroll
      for (int c = 0; c < 4; ++c)
        kf[c] = *(const bf16x8*)(Ksh + ql * 128 + (((hi + 2 * c) ^ (ql & 7)) << 4));
      // V fragments: rows ql / 32+ql, chunks hi / hi+2 at slot c^(ql&3)
      const int vb = ((ql >> 4) << 10) + ((ql & 15) << 6);
      bf16x8 va00 = *(const bf16x8*)(Vsh + vb + (((hi) ^ (ql & 3)) << 4));
      bf16x8 va01 = *(const bf16x8*)(Vsh + vb + (((hi + 2) ^ (ql & 3)) << 4));
      bf16x8 va10 = *(const bf16x8*)(Vsh + 2048 + vb + (((hi) ^ (ql & 3)) << 4));
      bf16x8 va11 = *(const bf16x8*)(Vsh + 2048 + vb + (((hi + 2) ^ (ql & 3)) << 4));

      f32x4 bvsB[4];
#pragma unroll
      for (int j = 0; j < 4; ++j) bvsB[j] = *(const f32x4*)(BpB + mykt * 32 + 8 * j);
      attn_chain(qfB, bvsB, kf[0], kf[1], kf[2], kf[3], va00, va01, va10, va11,
                 mykt == tB, ql, hi, oB0, oB1, plsB);
      if (mykt <= tA) {                     // wave-uniform
        f32x4 bvsA[4];
#pragma unroll
        for (int j = 0; j < 4; ++j) bvsA[j] = *(const f32x4*)(BpA + mykt * 32 + 8 * j);
        attn_chain(qfA, bvsA, kf[0], kf[1], kf[2], kf[3], va00, va01, va10, va11,
                   mykt == tA, ql, hi, oA0, oA1, plsA);
      }
    }
    db ^= 1;
  }

  // ---- cross-wave combine epilogue (aliased onto staging LDS) ----
  __syncthreads();                          // all waves done with staging LDS
  float* ldsF = (float*)lds;
  float* lsumbuf = ldsF + 8448;             // [2][256]
  float* rowinv = ldsF + 8960;              // [2][32]
  lsumbuf[(w * 2 + hi) * 32 + ql] = plsA;
  lsumbuf[256 + (w * 2 + hi) * 32 + ql] = plsB;
  if (w >= 2) {
    float* OA = ldsF + (w - 2) * 2112;          // Obuf[tile0][w-2]
    float* OB = ldsF + (2 + (w - 2)) * 2112;    // Obuf[tile1][w-2]
#pragma unroll
    for (int reg = 0; reg < 16; ++reg) {
      int d0 = (reg & 3) + 8 * (reg >> 2) + 4 * hi;
      OA[d0 * 33 + ql] = oA0[reg];
      OA[(d0 + 32) * 33 + ql] = oA1[reg];
      OB[d0 * 33 + ql] = oB0[reg];
      OB[(d0 + 32) * 33 + ql] = oB1[reg];
    }
  }
  __syncthreads();
  if (w < 2) {
    float* OA = ldsF + w * 2112;
    float* OB = ldsF + (2 + w) * 2112;
#pragma unroll
    for (int reg = 0; reg < 16; ++reg) {
      int d0 = (reg & 3) + 8 * (reg >> 2) + 4 * hi;
      OA[d0 * 33 + ql] += oA0[reg];
      OA[(d0 + 32) * 33 + ql] += oA1[reg];
      OB[d0 * 33 + ql] += oB0[reg];
      OB[(d0 + 32) * 33 + ql] += oB1[reg];
    }
  }
  __syncthreads();
  if (tid < 64) {
    int t = tid >> 5, q = tid & 31;
    float s = 0.f;
#pragma unroll
    for (int j = 0; j < 8; ++j) s += lsumbuf[t * 256 + j * 32 + q];
    rowinv[t * 32 + q] = frcp(s);
  }
  __syncthreads();
  // final write: d fastest -> 128B-contiguous global stores
#pragma unroll
  for (int it = 0; it < 16; ++it) {
    int i = it * 256 + tid;
    int t = i >> 11;
    int rem = i & 2047;
    int q = rem >> 6, d = rem & 63;
    float val = (ldsF[t * 4224 + d * 33 + q] + ldsF[t * 4224 + 2112 + d * 33 + q])
                * rowinv[t * 32 + q];
    int row = b * 2048 + (t ? q0B : q0A) + q;
    Ob[(size_t)row * 1024 + h * 64 + d] = f2b(val);
  }
}

extern "C" void kernel_launch(void* const* d_in, const int* in_sizes, int n_in,
                              void* d_out, int out_size, void* d_ws, size_t ws_size,
                              hipStream_t stream) {
  (void)in_sizes; (void)n_in; (void)out_size; (void)ws_size;
  const float* inp  = (const float*)d_in[0];
  const float* bias = (const float*)d_in[1];
  // d_in[2] = attn_mask (causal, recomputed in-kernel)
  const float* wq = (const float*)d_in[3];
  const float* wk = (const float*)d_in[4];
  const float* wv = (const float*)d_in[5];
  const float* wo = (const float*)d_in[6];
  float* out = (float*)d_out;

  unsigned short* Xb   = (unsigned short*)d_ws;     // 4096x1024 bf16
  unsigned short* Wcat = Xb + 4194304;              // 4 x 1024x1024 bf16
  unsigned short* Qb   = Wcat + 4194304;            // 4096x1024
  unsigned short* Kb   = Qb + 4194304;              // 4096x1024
  unsigned short* Vt   = Kb + 4194304;              // (2*16*64) x 2048
  unsigned short* Ob   = Vt + 4194304;              // 4096x1024

  convert_kernel<<<8192, 256, 0, stream>>>(inp, wq, wk, wv, wo, Xb, Wcat);
  gemm_qkv<<<dim3(32, 8, 3), dim3(256), 0, stream>>>(Xb, Wcat, Qb, Kb, Vt);
  attn_fwd<<<1024, 256, 0, stream>>>(Qb, Kb, Vt, bias, Ob);
  gemm_out<<<dim3(32, 8, 1), dim3(256), 0, stream>>>(Ob, Wcat + 3 * 1048576, out);
}